// Round 27
// baseline (196.998 us; speedup 1.0000x reference)
//
#include <hip/hip_runtime.h>

// Locally connected layer:
// out[b,o,h,w] = sum_{c,i,j} x[b,c,h+i,w+j] * W[o,c,h,w,i,j] + bias[o,h,w]
// x: [32,32,64,64] f32, W: [64,32,62,62,3,3] f32, bias: [64,62,62] f32
// out: [32,64,62,62] f32
//
// R27: TRANSPOSED lane layout. lane = (og=lane>>4, wg=lane&15): wave covers
// 4 o's; block's 4 waves cover different batch-octets (all 32 per block).
// Mechanism: same-address lanes within ONE instruction are coalescer-merged
// (free); so x duplication moves intra-wave: each XLD touches 4 lines (was
// 16) -> TA requests halved. Each lane reads only its own o-row from LDS:
// 9 ds_read (was 18). Block stages 4 W rows cooperatively (1 row per wave,
// 3 gll each; was 6/wave + twin duplication).
// Sync: one raw s_barrier per channel (NO __syncthreads - it drains vmcnt).
// Race-free: each wave WAITV(6)-retires its OWN gll(c) before barrier(c);
// readers read after barrier. STAGE(c+1) mid-channel post-barrier writes
// the buffer nobody reads this channel. Depth-1 is enough: gll ages a full
// channel (~10K cy >> 900 HBM).
// FIFO (R11/R20 lessons): queue at channel top = gll(c) 3 + x(c){A,B} 6;
// WAITV(6) retires exactly gll(c). In-channel refills precede STAGE(c+1);
// FMA(b6,b7) wait x only (older than the fresh gll). x(c+1) issued last.
// LDS rows padded to 1148 floats: og-row bases stagger banks {0,28,24,20}
// -> ds_read_b128 hits the 8-access/bank minimum (conflict-free).
// Validated pieces: wide W staging (R25), pin-before-FENCE (R20), DPP halo
// 0x101 (R8), chunked XCD swizzle (R3), nontemporal stores, plain
// launch_bounds (min-waves clause spills: R4/R8).

#define C_  32
#define B_  32
#define O_  64
#define H_  64
#define W_  64
#define OH_ 62
#define OW_ 62

typedef float vfloat2 __attribute__((ext_vector_type(2)));
typedef float vfloat4 __attribute__((ext_vector_type(4)));

#define GLL16(gaddr, laddr)                                                     \
    __builtin_amdgcn_global_load_lds(                                           \
        (const __attribute__((address_space(1))) void*)(gaddr),                 \
        (__attribute__((address_space(3))) void*)(laddr), 16, 0, 0)

#define GLL4(gaddr, laddr)                                                      \
    __builtin_amdgcn_global_load_lds(                                           \
        (const __attribute__((address_space(1))) void*)(gaddr),                 \
        (__attribute__((address_space(3))) void*)(laddr), 4, 0, 0)

// dst[lane] = src[lane+1] within each 16-lane row (validated R8); og group
// boundaries coincide with DPP rows, so the halo stays within one og.
__device__ __forceinline__ float dpp_nextlane(float v) {
    return __int_as_float(__builtin_amdgcn_update_dpp(
        0, __float_as_int(v), 0x101, 0xf, 0xf, true));
}

#define WAITV(n) do {                                                           \
        asm volatile("s_waitcnt vmcnt(" #n ")" ::: "memory");                   \
        __builtin_amdgcn_sched_barrier(0);                                      \
    } while (0)

#define FENCE() __builtin_amdgcn_sched_barrier(0)

__global__ __launch_bounds__(256)
void lcl_kernel(const float* __restrict__ x,
                const float* __restrict__ Wt,
                const float* __restrict__ bias,
                float* __restrict__ out) {
    // [2 buffers][4 o-rows][1148 floats]: row stride 4592 B (16B-aligned,
    // bank-stagger 28/row); 2232 B used per row. Total 36736 B -> 4 blk/CU.
    __shared__ __attribute__((aligned(16))) float ldsW[2][4][1148];

    // ---- chunked XCD swizzle (hw: XCD = blockIdx.x % 8); 992 = 8 * 124.
    // oq fast -> the 16 o-quad blocks of one h sit on one XCD (x L2-hot).
    const int i0      = blockIdx.x;
    const int logical = (i0 & 7) * 124 + (i0 >> 3);
    const int oq      = logical & 15;                // o-quad 0..15
    const int h       = logical >> 4;                // 0..61

    const int wv_i  = threadIdx.x >> 6;              // wave 0..3: batch octet
    const int lane  = threadIdx.x & 63;
    const int og    = lane >> 4;                     // this lane's o within quad
    const int wg    = lane & 15;                     // w0 = 4*wg
    const int w0    = wg * 4;
    const int o     = (oq << 2) + og;
    const int bbase = wv_i * 8;                      // batches bbase..bbase+7
    const bool full = (wg < 15);                     // wg15 stores only w=60,61

    float acc[8][4];
#pragma unroll
    for (int bi = 0; bi < 8; ++bi)
#pragma unroll
        for (int wi = 0; wi < 4; ++wi) acc[bi][wi] = 0.f;

    // W row this WAVE stages (row wv_i of the quad): o_st = oq*4 + wv_i
    const long wrow_st = (long)((oq << 2) + wv_i) * (C_ * 34596) + (long)h * 558;

    // x byte base for (bbase, h, w0); same for all og (coalescer merges)
    const char* xb0 = (const char*)x + (unsigned)bbase * 524288u
                      + (unsigned)h * 256u + (unsigned)wg * 16u;

    // stage one 2232-B W row: 2x dwordx4 gll + dword tail [1976,2232)
    // (overlap [1976,2048) double-written with identical data; R25-validated)
#define STAGE_W(buf, cidx) do {                                                 \
        const char* s_ = (const char*)(Wt + wrow_st + (long)(cidx) * 34596);    \
        char* d_ = (char*)&ldsW[buf][wv_i][0];                                  \
        GLL16(s_ + lane * 16, d_);                                              \
        GLL16(s_ + 1024 + lane * 16, d_ + 1024);                                \
        GLL4(s_ + 1976 + lane * 4, d_ + 1976);                                  \
    } while (0)

    // lane's 36 W floats of ITS o-row (9 ds_read_b128; og-row stagger makes
    // this the 8-access/bank minimum). wg15 floats 558.. are pad garbage ->
    // only feed acc[..][2/3], never stored for that lane.
#define DSREAD_W(buf) do {                                                      \
        const char* r_ = (const char*)&ldsW[buf][og][0] + wg * 144;             \
        _Pragma("unroll")                                                       \
        for (int q_ = 0; q_ < 9; ++q_)                                          \
            wq[q_] = *reinterpret_cast<const vfloat4*>(r_ + q_ * 16);           \
    } while (0)

#define WQ(t) (wq[(t) >> 2][(t) & 3])

    // issue 3 float4 rows of batch bbase+bi_ for channel cidx into slot s_
    // (address og-independent -> 4 og groups merge to 4 line-requests)
#define XLD(s_, cidx, bi_) do {                                                 \
        const char* p_ = xb0 + (unsigned)(bi_) * 524288u                        \
                         + (unsigned)(cidx) * 16384u;                           \
        xv##s_[0] = *reinterpret_cast<const float4*>(p_);                       \
        xv##s_[1] = *reinterpret_cast<const float4*>(p_ + 256);                 \
        xv##s_[2] = *reinterpret_cast<const float4*>(p_ + 512);                 \
    } while (0)

    // expand slot s_ via DPP halo, 36 FMAs into acc[bi_]
#define FMA1(s_, bi_) do {                                                      \
        float xr_[3][6];                                                        \
        _Pragma("unroll")                                                       \
        for (int r_ = 0; r_ < 3; ++r_) {                                        \
            xr_[r_][0] = xv##s_[r_].x; xr_[r_][1] = xv##s_[r_].y;               \
            xr_[r_][2] = xv##s_[r_].z; xr_[r_][3] = xv##s_[r_].w;               \
            xr_[r_][4] = dpp_nextlane(xv##s_[r_].x);                            \
            xr_[r_][5] = dpp_nextlane(xv##s_[r_].y);                            \
        }                                                                       \
        _Pragma("unroll")                                                       \
        for (int wi_ = 0; wi_ < 4; ++wi_)                                       \
        _Pragma("unroll")                                                       \
        for (int ii_ = 0; ii_ < 3; ++ii_)                                       \
        _Pragma("unroll")                                                       \
        for (int j_ = 0; j_ < 3; ++j_)                                          \
            acc[bi_][wi_] = fmaf(xr_[ii_][wi_ + j_],                            \
                                 WQ(wi_ * 9 + ii_ * 3 + j_), acc[bi_][wi_]);    \
    } while (0)

    vfloat4 wq[9];
    float4  xvA[3], xvB[3], xvC[3];

    // ---- prologue: stage c=0, then x(0) slots A,B (gll oldest in queue)
    STAGE_W(0, 0);
    XLD(A, 0, 0);
    XLD(B, 0, 1);

    for (int c = 0; c < C_; ++c) {
        const int p = c & 1;
        // queue at top: gll(c) 3 (oldest) + x(c){A,B} 6. WAITV(6) retires
        // exactly gll(c) -> own staged row is in LDS before the barrier.
        WAITV(6);
        FENCE();
        __builtin_amdgcn_s_barrier();     // all waves' gll(c) landed
        FENCE();
        DSREAD_W(p);                      // 9 ds_read_b128 (lgkm auto)
        FENCE();
        XLD(C, c, 2); FMA1(A, 0);         // FMA waits x only (oldest)
        FENCE();
        XLD(A, c, 3); FMA1(B, 1);
        FENCE();
        XLD(B, c, 4); FMA1(C, 2);
        FENCE();
        XLD(C, c, 5); FMA1(A, 3);
        FENCE();
        XLD(A, c, 6); FMA1(B, 4);
        FENCE();
        XLD(B, c, 7); FMA1(C, 5);
        FENCE();
        if (c + 1 < C_) STAGE_W(p ^ 1, c + 1);  // writes buffer nobody reads
        FENCE();                                // this channel (race-free)
        FMA1(A, 6);                       // x(b6),x(b7) older than the gll ->
        FMA1(B, 7);                       // clean waits
        FENCE();
        if (c + 1 < C_) {                 // x(c+1): youngest, after gll(c+1)
            XLD(A, c + 1, 0);             // -> invariant restored for c+1
            XLD(B, c + 1, 1);
        }
    }

    // ---- epilogue: bias + nontemporal float2 stores (8B-aligned)
    const float* brow = bias + ((long)o * OH_ + h) * OW_ + w0;
    float2 bv0 = *reinterpret_cast<const float2*>(brow);
    float2 bv1;
    if (full) bv1 = *reinterpret_cast<const float2*>(brow + 2);
    else { bv1.x = 0.f; bv1.y = 0.f; }

#pragma unroll
    for (int bi = 0; bi < 8; ++bi) {
        float* orow = out + (((long)(bbase + bi) * O_ + o) * OH_ + h) * OW_ + w0;
        vfloat2 s0; s0.x = acc[bi][0] + bv0.x; s0.y = acc[bi][1] + bv0.y;
        __builtin_nontemporal_store(s0, reinterpret_cast<vfloat2*>(orow));
        if (full) {
            vfloat2 s1; s1.x = acc[bi][2] + bv1.x; s1.y = acc[bi][3] + bv1.y;
            __builtin_nontemporal_store(s1, reinterpret_cast<vfloat2*>(orow) + 1);
        }
    }

#undef STAGE_W
#undef DSREAD_W
#undef WQ
#undef XLD
#undef FMA1
}

extern "C" void kernel_launch(void* const* d_in, const int* in_sizes, int n_in,
                              void* d_out, int out_size, void* d_ws, size_t ws_size,
                              hipStream_t stream) {
    const float* x    = (const float*)d_in[0];
    const float* Wt   = (const float*)d_in[1];
    const float* bias = (const float*)d_in[2];
    float* out        = (float*)d_out;

    dim3 grid(16 * OH_);   // 992 blocks (16 o-quads x 62 h), XCD-swizzled
    dim3 block(256);
    lcl_kernel<<<grid, block, 0, stream>>>(x, Wt, bias, out);
}

// Round 28
// 144.381 us; speedup vs baseline: 1.3644x; 1.3644x over previous
//
#include <hip/hip_runtime.h>

// Locally connected layer:
// out[b,o,h,w] = sum_{c,i,j} x[b,c,h+i,w+j] * W[o,c,h,w,i,j] + bias[o,h,w]
// x: [32,32,64,64] f32, W: [64,32,62,62,3,3] f32, bias: [64,62,62] f32
// out: [32,64,62,62] f32
//
// R28 = R25 (best: 137us bench) + WAVE PHASE-STAGGER: wave w processes
// channels in order (c + 8w) mod 32. R25/R21 budget analysis: elapsed =
// TA + LDS + VALU summed (waves in near-lockstep all hit the same pipe
// simultaneously, then all wait). Staggering puts co-resident waves in
// different phases -> pipes overlap. Same work, same FIFO invariants
// (indices remapped; mod-32 wrap replaces the tail clamp). fp32 per-wave
// sum order changes (same 32 terms) -> within tolerance (0.25 vs 1.74).
// Validated pieces: wide W staging 2xGLL16+GLL4 tail (R25), pin-before-
// FENCE (R20: VGPR 64->104), x-oldest/gll-youngest FIFO (R21), batch-split
// twins (R20), 2 o's/wave, barrier-free (R12), DPP halo 0x101 (R8),
// chunked XCD swizzle (R3), nontemporal stores, plain launch_bounds
// (min-waves clause spills: R4/R8).

#define C_  32
#define B_  32
#define O_  64
#define H_  64
#define W_  64
#define OH_ 62
#define OW_ 62

typedef float vfloat2 __attribute__((ext_vector_type(2)));
typedef float vfloat4 __attribute__((ext_vector_type(4)));

#define GLL16(gaddr, laddr)                                                     \
    __builtin_amdgcn_global_load_lds(                                           \
        (const __attribute__((address_space(1))) void*)(gaddr),                 \
        (__attribute__((address_space(3))) void*)(laddr), 16, 0, 0)

#define GLL4(gaddr, laddr)                                                      \
    __builtin_amdgcn_global_load_lds(                                           \
        (const __attribute__((address_space(1))) void*)(gaddr),                 \
        (__attribute__((address_space(3))) void*)(laddr), 4, 0, 0)

// dst[lane] = src[lane+1] within each 16-lane row (validated R8)
__device__ __forceinline__ float dpp_nextlane(float v) {
    return __int_as_float(__builtin_amdgcn_update_dpp(
        0, __float_as_int(v), 0x101, 0xf, 0xf, true));
}

#define WAITV(n) do {                                                           \
        asm volatile("s_waitcnt vmcnt(" #n ")" ::: "memory");                   \
        __builtin_amdgcn_sched_barrier(0);                                      \
    } while (0)

#define FENCE() __builtin_amdgcn_sched_barrier(0)

__global__ __launch_bounds__(256)
void lcl_kernel(const float* __restrict__ x,
                const float* __restrict__ Wt,
                const float* __restrict__ bias,
                float* __restrict__ out) {
    // W rows: [2 buffers][4 waves][2 o's][576 floats] = 36864 B; slot =
    // 2304 B (16B multiple), base 16B-aligned for dwordx4 LDS writes.
    __shared__ __attribute__((aligned(16))) float ldsW[2][4][2][576];

    // ---- chunked XCD swizzle (hw: XCD = blockIdx.x % 8); 992 = 8 * 124
    const int i0      = blockIdx.x;
    const int logical = (i0 & 7) * 124 + (i0 >> 3);
    const int bhalf   = logical & 1;                 // twin: batches 0-15/16-31
    const int pair    = logical >> 1;                // 0..495
    const int og      = pair & 7;                    // o-octet (fast)
    const int h       = pair >> 3;                   // 0..61

    const int wv_i = threadIdx.x >> 6;               // wave 0..3
    const int o0   = (og << 3) + (wv_i << 1);        // this wave: o0, o0+1
    const int lane = threadIdx.x & 63;
    const int wg   = lane & 15;                      // w0 = 4*wg
    const int bg   = lane >> 4;                      // 4 batches per bg
    const int w0   = wg * 4;
    const int b0   = bhalf * 16 + bg * 4;
    const bool full = (wg < 15);                     // wg15 stores only w=60,61

    // phase stagger: wave w starts at channel 8w; order (c + 8w) & 31
    const int coff = wv_i << 3;

    float acc0[4][4], acc1[4][4];
#pragma unroll
    for (int bi = 0; bi < 4; ++bi)
#pragma unroll
        for (int wi = 0; wi < 4; ++wi) { acc0[bi][wi] = 0.f; acc1[bi][wi] = 0.f; }

    // W row bases (floats): o*C*34596 + h*558
    const long wrow0 = (long)o0 * (C_ * 34596) + (long)h * 558;
    const long wrow1 = wrow0 + (long)C_ * 34596;     // o0+1

    // x byte base for (b0, h, w0)
    const char* xb0 = (const char*)x + (unsigned)b0 * 524288u
                      + (unsigned)h * 256u + (unsigned)wg * 16u;

    // stage one 2232-B W row: 2x dwordx4 gll + dword tail [1976,2232)
    // (overlap [1976,2048) double-written with identical data; R25-validated)
#define STAGE_ROW(srow, drow) do {                                              \
        GLL16((srow) + lane * 16, (drow));                                      \
        GLL16((srow) + 1024 + lane * 16, (drow) + 1024);                        \
        GLL4((srow) + 1976 + lane * 4, (drow) + 1976);                          \
    } while (0)

#define STAGE_W2(buf, cidx) do {                                                \
        const char* s0_ = (const char*)(Wt + wrow0 + (long)(cidx) * 34596);     \
        const char* s1_ = (const char*)(Wt + wrow1 + (long)(cidx) * 34596);     \
        char* d0_ = (char*)&ldsW[buf][wv_i][0][0];                              \
        char* d1_ = (char*)&ldsW[buf][wv_i][1][0];                              \
        STAGE_ROW(s0_, d0_);                                                    \
        STAGE_ROW(s1_, d1_);                                                    \
    } while (0)

    // lane's 36 W floats for o-slot oo_ (9 ds_read_b128; 144-B lane stride =
    // 2-way alias + 4-way bg broadcast, conflict-free per counters).
#define DSREAD_W(buf, oo_) do {                                                 \
        const char* r_ = (const char*)&ldsW[buf][wv_i][oo_][0] + wg * 144;      \
        _Pragma("unroll")                                                       \
        for (int q_ = 0; q_ < 9; ++q_)                                          \
            wq[q_] = *reinterpret_cast<const vfloat4*>(r_ + q_ * 16);           \
    } while (0)

#define WQ(t) (wq[(t) >> 2][(t) & 3])

    // issue 3 float4 rows of batch b0+bi_ for channel cidx into slot s_
#define XLD(s_, cidx, bi_) do {                                                 \
        const char* p_ = xb0 + (unsigned)(bi_) * 524288u                        \
                         + (unsigned)(cidx) * 16384u;                           \
        xv##s_[0] = *reinterpret_cast<const float4*>(p_);                       \
        xv##s_[1] = *reinterpret_cast<const float4*>(p_ + 256);                 \
        xv##s_[2] = *reinterpret_cast<const float4*>(p_ + 512);                 \
    } while (0)

    // expand slot s_ via DPP halo, 36 FMAs into ACC[bi_]
#define FMA1(ACC, s_, bi_) do {                                                 \
        float xr_[3][6];                                                        \
        _Pragma("unroll")                                                       \
        for (int r_ = 0; r_ < 3; ++r_) {                                        \
            xr_[r_][0] = xv##s_[r_].x; xr_[r_][1] = xv##s_[r_].y;               \
            xr_[r_][2] = xv##s_[r_].z; xr_[r_][3] = xv##s_[r_].w;               \
            xr_[r_][4] = dpp_nextlane(xv##s_[r_].x);                            \
            xr_[r_][5] = dpp_nextlane(xv##s_[r_].y);                            \
        }                                                                       \
        _Pragma("unroll")                                                       \
        for (int wi_ = 0; wi_ < 4; ++wi_)                                       \
        _Pragma("unroll")                                                       \
        for (int ii_ = 0; ii_ < 3; ++ii_)                                       \
        _Pragma("unroll")                                                       \
        for (int j_ = 0; j_ < 3; ++j_)                                          \
            ACC[bi_][wi_] = fmaf(xr_[ii_][wi_ + j_],                            \
                                 WQ(wi_ * 9 + ii_ * 3 + j_), ACC[bi_][wi_]);    \
    } while (0)

    vfloat4 wq[9];
    float4  xvA[3], xvB[3], xvC[3], xvD[3];

    // ---- prologue: depth-2 W prefetch (staggered channels), then x(coff)
    STAGE_W2(0, coff);
    STAGE_W2(1, (coff + 1) & 31);
    XLD(A, coff, 0);
    XLD(B, coff, 1);
    XLD(C, coff, 2);
    XLD(D, coff, 3);

    for (int c = 0; c < C_; ++c) {
        const int p  = c & 1;
        const int c1 = (c + 1 + coff) & 31;          // next channel (actual)
        const int c2 = (c + 2 + coff) & 31;          // stage target (actual)
        // invariant: outstanding = gll(c) 6 + x(c) 12 + gll(c+1) 6 = 24.
        // vmcnt(18) retires exactly gll(c) (2 iterations old -> ~free).
        WAITV(18);
        DSREAD_W(p, 0);                   // wq := o0 row
        FENCE();
        FMA1(acc0, A, 0);                 // waits x(c) only (oldest in queue)
        FMA1(acc0, B, 1);
        FMA1(acc0, C, 2);
        FMA1(acc0, D, 3);
        FENCE();
        DSREAD_W(p, 1);                   // wq := o1 row (same regs)
        FENCE();
        FMA1(acc1, A, 0);
        FMA1(acc1, B, 1);
        FMA1(acc1, C, 2);
        FMA1(acc1, D, 3);
        FENCE();
        if (c + 1 < C_) {                 // x(next): oldest VMEM of next iter
            XLD(A, c1, 0);
            XLD(B, c1, 1);
            XLD(C, c1, 2);
            XLD(D, c1, 3);
        }
        FENCE();
        // gll(next+1): YOUNGEST. At c=30,31 the mod-32 wrap stages an
        // already-processed channel (never read; keeps the count invariant,
        // always in-bounds). Buf p was fully ds_read above (no race).
        STAGE_W2(p, c2);
    }

    // ---- epilogue: bias + nontemporal float2 stores (8B-aligned), 2 o's
#pragma unroll
    for (int oo = 0; oo < 2; ++oo) {
        const int oc = o0 + oo;
        const float* brow = bias + ((long)oc * OH_ + h) * OW_ + w0;
        float2 bv0 = *reinterpret_cast<const float2*>(brow);
        float2 bv1;
        if (full) bv1 = *reinterpret_cast<const float2*>(brow + 2);
        else { bv1.x = 0.f; bv1.y = 0.f; }
#pragma unroll
        for (int bi = 0; bi < 4; ++bi) {
            const float* a_ = oo ? acc1[bi] : acc0[bi];
            float* orow = out + (((long)(b0 + bi) * O_ + oc) * OH_ + h) * OW_ + w0;
            vfloat2 s0; s0.x = a_[0] + bv0.x; s0.y = a_[1] + bv0.y;
            __builtin_nontemporal_store(s0, reinterpret_cast<vfloat2*>(orow));
            if (full) {
                vfloat2 s1; s1.x = a_[2] + bv1.x; s1.y = a_[3] + bv1.y;
                __builtin_nontemporal_store(s1, reinterpret_cast<vfloat2*>(orow) + 1);
            }
        }
    }

#undef STAGE_ROW
#undef STAGE_W2
#undef DSREAD_W
#undef WQ
#undef XLD
#undef FMA1
}

extern "C" void kernel_launch(void* const* d_in, const int* in_sizes, int n_in,
                              void* d_out, int out_size, void* d_ws, size_t ws_size,
                              hipStream_t stream) {
    const float* x    = (const float*)d_in[0];
    const float* Wt   = (const float*)d_in[1];
    const float* bias = (const float*)d_in[2];
    float* out        = (float*)d_out;

    dim3 grid(992);   // (62 h x 8 og x 2 batch-halves), XCD-swizzled
    dim3 block(256);
    lcl_kernel<<<grid, block, 0, stream>>>(x, Wt, bias, out);
}

// Round 29
// 137.947 us; speedup vs baseline: 1.4281x; 1.0466x over previous
//
#include <hip/hip_runtime.h>

// Locally connected layer:
// out[b,o,h,w] = sum_{c,i,j} x[b,c,h+i,w+j] * W[o,c,h,w,i,j] + bias[o,h,w]
// x: [32,32,64,64] f32, W: [64,32,62,62,3,3] f32, bias: [64,62,62] f32
// out: [32,64,62,62] f32
//
// R29 = R25 + CROSS-CHANNEL wq PREFETCH: DSREAD for channel c+1 happens at
// the END of channel c, after a free WAITV(18) (its gll is a full channel
// old). The ds_read latency hides under the next channel's first FMAs
// (which wait only on x). This removes the last synchronous in-loop stall:
// R25/R26 both paid ~150-250 cy lgkm at every channel top (R26's null
// showed the MID-channel stall wasn't it; the TOP one remained).
// Channel body: FMA acc0 x4 | FMA acc1 x4 | XLD(c+1) | STAGE(c+2, buf c&1
// - channel c's W already in regs, buffer dead) | WAITV(18) retires
// gll(c+1) | DSREAD wq0,wq1 <- buf (c+1)&1.
// Queue invariant at WAITV: [gll(c+1) 6 | x(c+1) 12 | gll(c+2) 6] = 24.
// First FMA of channel c: outstanding [x(c) 12 | gll(c+1) 6], slot A =
// oldest -> no fresh-gll blockage (R11/R20 FIFO lessons).
// Prologue order STAGE(0), XLD(0), STAGE(1): x(0) never queues behind
// fresh gll. Tail: XLD/STAGE/DSREAD guarded by c+1<C_; STAGE clamp keeps
// counts; WAITV no-op at c=31.
// Validated: wide W staging 2xGLL16+GLL4 (R25), pin-before-FENCE (R20),
// x-oldest/gll-youngest (R21), batch-split twins (R20), 2 o's/wave,
// barrier-free (R12), DPP halo 0x101 (R8), chunked XCD swizzle (R3),
// nontemporal stores, plain launch_bounds (min-waves spills: R4/R8).

#define C_  32
#define B_  32
#define O_  64
#define H_  64
#define W_  64
#define OH_ 62
#define OW_ 62

typedef float vfloat2 __attribute__((ext_vector_type(2)));
typedef float vfloat4 __attribute__((ext_vector_type(4)));

#define GLL16(gaddr, laddr)                                                     \
    __builtin_amdgcn_global_load_lds(                                           \
        (const __attribute__((address_space(1))) void*)(gaddr),                 \
        (__attribute__((address_space(3))) void*)(laddr), 16, 0, 0)

#define GLL4(gaddr, laddr)                                                      \
    __builtin_amdgcn_global_load_lds(                                           \
        (const __attribute__((address_space(1))) void*)(gaddr),                 \
        (__attribute__((address_space(3))) void*)(laddr), 4, 0, 0)

// dst[lane] = src[lane+1] within each 16-lane row (validated R8)
__device__ __forceinline__ float dpp_nextlane(float v) {
    return __int_as_float(__builtin_amdgcn_update_dpp(
        0, __float_as_int(v), 0x101, 0xf, 0xf, true));
}

#define WAITV(n) do {                                                           \
        asm volatile("s_waitcnt vmcnt(" #n ")" ::: "memory");                   \
        __builtin_amdgcn_sched_barrier(0);                                      \
    } while (0)

#define FENCE() __builtin_amdgcn_sched_barrier(0)

__global__ __launch_bounds__(256)
void lcl_kernel(const float* __restrict__ x,
                const float* __restrict__ Wt,
                const float* __restrict__ bias,
                float* __restrict__ out) {
    // W rows: [2 buffers][4 waves][2 o's][576 floats] = 36864 B; slot =
    // 2304 B (16B multiple), base 16B-aligned for dwordx4 LDS writes.
    __shared__ __attribute__((aligned(16))) float ldsW[2][4][2][576];

    // ---- chunked XCD swizzle (hw: XCD = blockIdx.x % 8); 992 = 8 * 124
    const int i0      = blockIdx.x;
    const int logical = (i0 & 7) * 124 + (i0 >> 3);
    const int bhalf   = logical & 1;                 // twin: batches 0-15/16-31
    const int pair    = logical >> 1;                // 0..495
    const int og      = pair & 7;                    // o-octet (fast)
    const int h       = pair >> 3;                   // 0..61

    const int wv_i = threadIdx.x >> 6;               // wave 0..3
    const int o0   = (og << 3) + (wv_i << 1);        // this wave: o0, o0+1
    const int lane = threadIdx.x & 63;
    const int wg   = lane & 15;                      // w0 = 4*wg
    const int bg   = lane >> 4;                      // 4 batches per bg
    const int w0   = wg * 4;
    const int b0   = bhalf * 16 + bg * 4;
    const bool full = (wg < 15);                     // wg15 stores only w=60,61

    float acc0[4][4], acc1[4][4];
#pragma unroll
    for (int bi = 0; bi < 4; ++bi)
#pragma unroll
        for (int wi = 0; wi < 4; ++wi) { acc0[bi][wi] = 0.f; acc1[bi][wi] = 0.f; }

    // W row bases (floats): o*C*34596 + h*558
    const long wrow0 = (long)o0 * (C_ * 34596) + (long)h * 558;
    const long wrow1 = wrow0 + (long)C_ * 34596;     // o0+1

    // x byte base for (b0, h, w0)
    const char* xb0 = (const char*)x + (unsigned)b0 * 524288u
                      + (unsigned)h * 256u + (unsigned)wg * 16u;

    // stage one 2232-B W row: 2x dwordx4 gll + dword tail [1976,2232)
    // (overlap [1976,2048) double-written with identical data; R25-validated)
#define STAGE_ROW(srow, drow) do {                                              \
        GLL16((srow) + lane * 16, (drow));                                      \
        GLL16((srow) + 1024 + lane * 16, (drow) + 1024);                        \
        GLL4((srow) + 1976 + lane * 4, (drow) + 1976);                          \
    } while (0)

#define STAGE_W2(buf, cidx) do {                                                \
        const char* s0_ = (const char*)(Wt + wrow0 + (long)(cidx) * 34596);     \
        const char* s1_ = (const char*)(Wt + wrow1 + (long)(cidx) * 34596);     \
        char* d0_ = (char*)&ldsW[buf][wv_i][0][0];                              \
        char* d1_ = (char*)&ldsW[buf][wv_i][1][0];                              \
        STAGE_ROW(s0_, d0_);                                                    \
        STAGE_ROW(s1_, d1_);                                                    \
    } while (0)

    // lane's 36 W floats for o-slot oo_ into array WQA (9 ds_read_b128;
    // 144-B lane stride = 2-way alias + 4-way bg broadcast, conflict-free).
#define DSREAD_W(WQA, buf, oo_) do {                                            \
        const char* r_ = (const char*)&ldsW[buf][wv_i][oo_][0] + wg * 144;      \
        _Pragma("unroll")                                                       \
        for (int q_ = 0; q_ < 9; ++q_)                                          \
            WQA[q_] = *reinterpret_cast<const vfloat4*>(r_ + q_ * 16);          \
    } while (0)

    // issue 3 float4 rows of batch b0+bi_ for channel cidx into slot s_
#define XLD(s_, cidx, bi_) do {                                                 \
        const char* p_ = xb0 + (unsigned)(bi_) * 524288u                        \
                         + (unsigned)(cidx) * 16384u;                           \
        xv##s_[0] = *reinterpret_cast<const float4*>(p_);                       \
        xv##s_[1] = *reinterpret_cast<const float4*>(p_ + 256);                 \
        xv##s_[2] = *reinterpret_cast<const float4*>(p_ + 512);                 \
    } while (0)

    // expand slot s_ via DPP halo, 36 FMAs into ACC[bi_] using W array WQA
#define FMA1(ACC, WQA, s_, bi_) do {                                            \
        float xr_[3][6];                                                        \
        _Pragma("unroll")                                                       \
        for (int r_ = 0; r_ < 3; ++r_) {                                        \
            xr_[r_][0] = xv##s_[r_].x; xr_[r_][1] = xv##s_[r_].y;               \
            xr_[r_][2] = xv##s_[r_].z; xr_[r_][3] = xv##s_[r_].w;               \
            xr_[r_][4] = dpp_nextlane(xv##s_[r_].x);                            \
            xr_[r_][5] = dpp_nextlane(xv##s_[r_].y);                            \
        }                                                                       \
        _Pragma("unroll")                                                       \
        for (int wi_ = 0; wi_ < 4; ++wi_)                                       \
        _Pragma("unroll")                                                       \
        for (int ii_ = 0; ii_ < 3; ++ii_)                                       \
        _Pragma("unroll")                                                       \
        for (int j_ = 0; j_ < 3; ++j_)                                          \
            ACC[bi_][wi_] = fmaf(xr_[ii_][wi_ + j_],                            \
                                 WQA[(wi_ * 9 + ii_ * 3 + j_) >> 2]             \
                                    [(wi_ * 9 + ii_ * 3 + j_) & 3],             \
                                 ACC[bi_][wi_]);                                \
    } while (0)

    vfloat4 wq0[9], wq1[9];
    float4  xvA[3], xvB[3], xvC[3], xvD[3];

    // ---- prologue: STAGE(0) | x(0) | STAGE(1) -> x(0) never behind a
    // fresher gll than gll(0). WAITV(18) retires gll(0); DSREAD wq(0).
    STAGE_W2(0, 0);
    XLD(A, 0, 0);
    XLD(B, 0, 1);
    XLD(C, 0, 2);
    XLD(D, 0, 3);
    STAGE_W2(1, 1);
    WAITV(18);                            // [gll0 6|x0 12|gll1 6] -> gll0 done
    DSREAD_W(wq0, 0, 0);
    DSREAD_W(wq1, 0, 1);

    for (int c = 0; c < C_; ++c) {
        const int p = c & 1;
        // entering: outstanding = [x(c) 12 (oldest) | gll(c+1) 6]; wq(c)
        // in regs (ds_read issued last iteration -> lgkm long landed).
        FENCE();
        FMA1(acc0, wq0, A, 0);            // waits x(c) slots only
        FMA1(acc0, wq0, B, 1);
        FMA1(acc0, wq0, C, 2);
        FMA1(acc0, wq0, D, 3);
        FMA1(acc1, wq1, A, 0);
        FMA1(acc1, wq1, B, 1);
        FMA1(acc1, wq1, C, 2);
        FMA1(acc1, wq1, D, 3);
        FENCE();
        if (c + 1 < C_) {                 // x(c+1): oldest VMEM of next iter
            XLD(A, c + 1, 0);
            XLD(B, c + 1, 1);
            XLD(C, c + 1, 2);
            XLD(D, c + 1, 3);
        }
        FENCE();
        if (c + 1 < C_) {                 // gll(c+2) -> buf p (channel c's W
            const int cn = (c + 2 < C_) ? (c + 2) : (C_ - 1);  // already in
            STAGE_W2(p, cn);              // regs; buffer dead). Clamp at tail.
        }
        FENCE();
        // retire gll(c+1) (issued one full channel ago -> ~free), then
        // prefetch wq(c+1); its lgkm hides under next iter's FMAs.
        WAITV(18);
        if (c + 1 < C_) {
            DSREAD_W(wq0, p ^ 1, 0);
            DSREAD_W(wq1, p ^ 1, 1);
        }
    }

    // ---- epilogue: bias + nontemporal float2 stores (8B-aligned), 2 o's
#pragma unroll
    for (int oo = 0; oo < 2; ++oo) {
        const int oc = o0 + oo;
        const float* brow = bias + ((long)oc * OH_ + h) * OW_ + w0;
        float2 bv0 = *reinterpret_cast<const float2*>(brow);
        float2 bv1;
        if (full) bv1 = *reinterpret_cast<const float2*>(brow + 2);
        else { bv1.x = 0.f; bv1.y = 0.f; }
#pragma unroll
        for (int bi = 0; bi < 4; ++bi) {
            const float* a_ = oo ? acc1[bi] : acc0[bi];
            float* orow = out + (((long)(b0 + bi) * O_ + oc) * OH_ + h) * OW_ + w0;
            vfloat2 s0; s0.x = a_[0] + bv0.x; s0.y = a_[1] + bv0.y;
            __builtin_nontemporal_store(s0, reinterpret_cast<vfloat2*>(orow));
            if (full) {
                vfloat2 s1; s1.x = a_[2] + bv1.x; s1.y = a_[3] + bv1.y;
                __builtin_nontemporal_store(s1, reinterpret_cast<vfloat2*>(orow) + 1);
            }
        }
    }

#undef STAGE_ROW
#undef STAGE_W2
#undef DSREAD_W
#undef XLD
#undef FMA1
}

extern "C" void kernel_launch(void* const* d_in, const int* in_sizes, int n_in,
                              void* d_out, int out_size, void* d_ws, size_t ws_size,
                              hipStream_t stream) {
    const float* x    = (const float*)d_in[0];
    const float* Wt   = (const float*)d_in[1];
    const float* bias = (const float*)d_in[2];
    float* out        = (float*)d_out;

    dim3 grid(992);   // (62 h x 8 og x 2 batch-halves), XCD-swizzled
    dim3 block(256);
    lcl_kernel<<<grid, block, 0, stream>>>(x, Wt, bias, out);
}